// Round 11
// baseline (217.320 us; speedup 1.0000x reference)
//
#include <hip/hip_runtime.h>
#include <cfloat>
#include <cstdint>

#define B_   8
#define N_   1024
#define H_   128
#define K_   20
#define EPS_ 1e-6f
#define R_   (B_ * 3 * N_)

typedef _Float16 half_t;
typedef _Float16 h8_t __attribute__((ext_vector_type(8)));
typedef _Float16 h4_t __attribute__((ext_vector_type(4)));
typedef __attribute__((ext_vector_type(4))) float f4_t;

__device__ inline void st4h(half_t* __restrict__ p, size_t off, f4_t v) {
    h4_t o;
    o[0] = (half_t)v[0]; o[1] = (half_t)v[1]; o[2] = (half_t)v[2]; o[3] = (half_t)v[3];
    *(h4_t*)(p + off) = o;
}

#define OFF_FC 0
#define OFF_D0 32768
#define OFF_W0 294912
#define OFF_D1 425984
#define OFF_W1 491520
#define OFF_WS 557056
#define W_TOT  688128
#define KNN_BLKS (B_ * N_ / 4)
#define CVT_BLKS ((W_TOT + 255) / 256)
#define TRD_TOT  98304   /* 3 layers x 128 x 256 */
#define TRS_TOT  49152   /* 3 layers x 128 x 128 */
#define TR_BLKS  ((TRD_TOT + TRS_TOT) / 256)

// ---------------------------------------------------------------------------
// prep (R11): conv FUSED into the selection loop. After the DPP/readlane min,
// j is wave-uniform -> ps[3j] is an LDS broadcast; the conv accumulation for
// round s uses the same neighbor order as the old opw[k] loop -> bit-identical.
// Removes the opw array, its LDS round-trip, and one block-wide sync; conv
// FMAs now hide the selection chain's DPP/readlane latency.
// ---------------------------------------------------------------------------
__global__ __launch_bounds__(256) void prep(const float* __restrict__ x,
                                            const float* __restrict__ Wf,
                                            const float* __restrict__ Wd,
                                            half_t* __restrict__ h1,
                                            const float* __restrict__ Wfc,
                                            const float* __restrict__ Wd0,
                                            const float* __restrict__ W0,
                                            const float* __restrict__ Wd1,
                                            const float* __restrict__ W1,
                                            const float* __restrict__ Wsc,
                                            half_t* __restrict__ w,
                                            float* __restrict__ wd0t,
                                            float* __restrict__ wst) {
    __shared__ float ps[N_ * 3];
    int t = threadIdx.x;

    if (blockIdx.x >= KNN_BLKS + CVT_BLKS) {
        int j = (blockIdx.x - KNN_BLKS - CVT_BLKS) * 256 + t;
        if (j < TRD_TOT) {
            int L = j >> 15, rem = j & 32767;
            int c = rem >> 8, o = rem & 255;
            wd0t[j] = Wd0[(size_t)(L + 1) * 65536 + o * 256 + 128 + c];
        } else {
            int k = j - TRD_TOT;
            int L = k >> 14, rem = k & 16383;
            int c = rem >> 7, o = rem & 127;
            wst[k] = Wsc[(size_t)(L + 1) * 32768 + o * 256 + 128 + c];
        }
        return;
    }
    if (blockIdx.x >= KNN_BLKS) {
        int bid = blockIdx.x - KNN_BLKS;
        int i = bid * 256 + t;
        if (i < W_TOT) {
            const float* src; int off;
            if (i < OFF_W0)      { if (i < OFF_D0) { src = Wfc; off = OFF_FC; }
                                   else            { src = Wd0; off = OFF_D0; } }
            else if (i < OFF_W1) { if (i < OFF_D1) { src = W0;  off = OFF_W0; }
                                   else            { src = Wd1; off = OFF_D1; } }
            else                 { if (i < OFF_WS) { src = W1;  off = OFF_W1; }
                                   else            { src = Wsc; off = OFF_WS; } }
            w[i] = (half_t)src[i - off];
        }
        return;
    }

    int wv = t >> 6, lane = t & 63;
    int b = blockIdx.x >> 8;
    int n = (blockIdx.x & 255) * 4 + wv;

    const float4* xb4 = (const float4*)(x + (size_t)b * N_ * 3);
    float4* ps4 = (float4*)ps;
    #pragma unroll
    for (int i = 0; i < 3; ++i) ps4[t + i * 256] = xb4[t + i * 256];
    __syncthreads();

    const float cx = ps[3 * n + 0], cy = ps[3 * n + 1], cz = ps[3 * n + 2];
    uint ku[16];
    #pragma unroll
    for (int k = 0; k < 16; ++k) {
        int j = lane + (k << 6);
        const float* pj = ps + 3 * j;
        float dx = pj[0] - cx, dy = pj[1] - cy, dz = pj[2] - cz;
        float d = fmaf(dz, dz, fmaf(dy, dy, dx * dx));
        ku[k] = (__float_as_uint(d) & 0xFFFFFC00u) | (uint)j;
    }

    // channel weights + hoisted center terms (before selection: conv is fused)
    float wf0[2], wf2[2], wd0c[2], wd2c[2];
    float bf[2][3], bg[2][3];
    #pragma unroll
    for (int c = 0; c < 2; ++c) {
        int ch = lane + c * 64;
        wf0[c]  = Wf[ch * 3 + 0];
        float wf1 = Wf[ch * 3 + 1];
        wf2[c]  = Wf[ch * 3 + 2];
        wd0c[c] = Wd[ch * 3 + 0];
        float wd1 = Wd[ch * 3 + 1];
        wd2c[c] = Wd[ch * 3 + 2];
        float df = wf1 - wf0[c], dg = wd1 - wd0c[c];
        bf[c][0] = df * cx; bf[c][1] = df * cy; bf[c][2] = df * cz;
        bg[c][0] = dg * cx; bg[c][1] = dg * cy; bg[c][2] = dg * cz;
    }
    float ax[2] = {0.f, 0.f}, ay[2] = {0.f, 0.f}, az[2] = {0.f, 0.f};

    for (int s = 0; s < K_; ++s) {
        uint a0 = min(min(ku[0],  ku[1]),  ku[2]);
        uint a1 = min(min(ku[3],  ku[4]),  ku[5]);
        uint a2 = min(min(ku[6],  ku[7]),  ku[8]);
        uint a3 = min(min(ku[9],  ku[10]), ku[11]);
        uint a4 = min(min(ku[12], ku[13]), ku[14]);
        uint m  = min(min(min(a0, a1), min(a2, a3)), min(a4, ku[15]));
        // 16-lane row min via DPP row_ror (no DS latency)
        m = min(m, (uint)__builtin_amdgcn_update_dpp(0, (int)m, 0x121, 0xF, 0xF, true));
        m = min(m, (uint)__builtin_amdgcn_update_dpp(0, (int)m, 0x122, 0xF, 0xF, true));
        m = min(m, (uint)__builtin_amdgcn_update_dpp(0, (int)m, 0x124, 0xF, 0xF, true));
        m = min(m, (uint)__builtin_amdgcn_update_dpp(0, (int)m, 0x128, 0xF, 0xF, true));
        uint mm = min(min((uint)__builtin_amdgcn_readlane((int)m, 0),
                          (uint)__builtin_amdgcn_readlane((int)m, 16)),
                      min((uint)__builtin_amdgcn_readlane((int)m, 32),
                          (uint)__builtin_amdgcn_readlane((int)m, 48)));
        int j = (int)(mm & 1023u);
        if ((j & 63) == lane) ku[j >> 6] = 0xFFFFFFFFu;

        // fused conv for neighbor j (wave-uniform -> LDS broadcast)
        const float* pj = ps + 3 * j;
        float nx = pj[0], ny = pj[1], nz = pj[2];
        float rx = fmaf(ny, cz, -(nz * cy));
        float ry = fmaf(nz, cx, -(nx * cz));
        float rz = fmaf(nx, cy, -(ny * cx));
        #pragma unroll
        for (int c = 0; c < 2; ++c) {
            float fx = fmaf(wf0[c], nx, fmaf(wf2[c], rx, bf[c][0]));
            float fy = fmaf(wf0[c], ny, fmaf(wf2[c], ry, bf[c][1]));
            float fz = fmaf(wf0[c], nz, fmaf(wf2[c], rz, bf[c][2]));
            float gx = fmaf(wd0c[c], nx, fmaf(wd2c[c], rx, bg[c][0]));
            float gy = fmaf(wd0c[c], ny, fmaf(wd2c[c], ry, bg[c][1]));
            float gz = fmaf(wd0c[c], nz, fmaf(wd2c[c], rz, bg[c][2]));
            float dot = fmaf(fz, gz, fmaf(fy, gy, fx * gx));
            float dsq = fmaf(gz, gz, fmaf(gy, gy, fmaf(gx, gx, EPS_)));
            float u = fminf(dot, 0.f) * __builtin_amdgcn_rcpf(dsq) * -0.8f;
            ax[c] = fmaf(u, gx, ax[c] + fx);
            ay[c] = fmaf(u, gy, ay[c] + fy);
            az[c] = fmaf(u, gz, az[c] + fz);
        }
    }

    const float inv = 1.0f / (float)K_;
    size_t r0 = ((size_t)b * 3) * N_ + n;
    #pragma unroll
    for (int c = 0; c < 2; ++c) {
        int ch = lane + c * 64;
        h1[(r0) * H_ + ch]          = (half_t)(ax[c] * inv);
        h1[(r0 + N_) * H_ + ch]     = (half_t)(ay[c] * inv);
        h1[(r0 + 2 * N_) * H_ + ch] = (half_t)(az[c] * inv);
    }
}

// ---------------------------------------------------------------------------
// Swizzled LDS helpers.
// ---------------------------------------------------------------------------
__device__ inline void stsw128(half_t* __restrict__ buf, int v, int n, int o, f4_t val) {
    int phys = (((o >> 3) ^ (n & 7)) * 8) + (o & 7);
    half_t* p = buf + (v * 16 + n) * 128 + phys;
    h4_t h;
    h[0] = (half_t)val[0]; h[1] = (half_t)val[1];
    h[2] = (half_t)val[2]; h[3] = (half_t)val[3];
    *(h4_t*)p = h;
}
__device__ inline f4_t ldsw128(const half_t* __restrict__ buf, int v, int n, int o) {
    int phys = (((o >> 3) ^ (n & 7)) * 8) + (o & 7);
    const half_t* p = buf + (v * 16 + n) * 128 + phys;
    h4_t x = *(const h4_t*)p;
    f4_t r;
    r[0] = (float)x[0]; r[1] = (float)x[1]; r[2] = (float)x[2]; r[3] = (float)x[3];
    return r;
}
__device__ inline void stsw256(half_t* __restrict__ buf, int v, int n, int o, f4_t val) {
    int phys = (((o >> 3) ^ (n & 7)) * 8) + (o & 7);
    half_t* p = buf + (v * 16 + n) * 256 + phys;
    h4_t h;
    h[0] = (half_t)val[0]; h[1] = (half_t)val[1];
    h[2] = (half_t)val[2]; h[3] = (half_t)val[3];
    *(h4_t*)p = h;
}
__device__ inline f4_t ldsw256(const half_t* __restrict__ buf, int v, int n, int o) {
    int phys = (((o >> 3) ^ (n & 7)) * 8) + (o & 7);
    const half_t* p = buf + (v * 16 + n) * 256 + phys;
    h4_t x = *(const h4_t*)p;
    f4_t r;
    r[0] = (float)x[0]; r[1] = (float)x[1]; r[2] = (float)x[2]; r[3] = (float)x[3];
    return r;
}

// ---------------------------------------------------------------------------
// block_full (R11): R10 body + COMPACT FIRST LDS (61440 -> 49152 => 3 blk/CU).
// Since R9 folded Ws into S0, HdL is dead after S0, enabling:
//  FIRST : HdL@0(24K) | a1L@12288(12K, over dead-HdL top) | hL@24576(12K,
//          dead after Hd stage) | a0L@24576(24K, over dead hL) | netL@0
//          (over dead HdL). Every WAR transition is separated by an existing
//          __syncthreads. FIRST also stores a0 directly (no qs staging; no
//          live-buffer aliasing) -> lower VGPR.
//  !FIRST: unchanged (50688B, 3 blk/CU). plP unroll 16->32 (fewer latency
//          groups on the cross-XCD L3 reads; serial sum order preserved).
// ---------------------------------------------------------------------------
template<bool FIRST, bool WRITE_OUT>
__global__ __launch_bounds__(512) void block_full(const half_t* __restrict__ Wfc,
                                                  const half_t* __restrict__ Wd0,
                                                  const half_t* __restrict__ W0,
                                                  const half_t* __restrict__ Wd1,
                                                  const half_t* __restrict__ Ws,
                                                  const half_t* __restrict__ W1,
                                                  const half_t* __restrict__ hprev,
                                                  const float* __restrict__ PpPrev,
                                                  const float* __restrict__ PW0,
                                                  const float* __restrict__ PW1,
                                                  half_t* __restrict__ outH,
                                                  float* __restrict__ PpOut) {
    __shared__ __align__(16) char smem[FIRST ? 49152 : 50688];
    half_t* hL   = (half_t*)(FIRST ? smem + 24576 : smem);
    half_t* HdL  = (half_t*)(smem);                               // FIRST only
    half_t* a0L  = (half_t*)(FIRST ? smem + 24576 : smem + 12288);
    half_t* netL = (half_t*)(FIRST ? smem : smem + 36864);
    half_t* a1L  = (half_t*)(FIRST ? smem + 12288 : smem + 24576);
    float* plP  = (float*)(smem + 12288);          // [3][128] (non-FIRST prologue)
    float* plD0 = (float*)(smem + 12288 + 1536);   // [3][256]
    float* plWs = (float*)(smem + 49152 - (FIRST ? 49152 : 1536)); // dummy for FIRST
    if (!FIRST) plWs = (float*)(smem + 49152);

    const int t = threadIdx.x;
    const int lane = t & 63, wm = t >> 6;            // wm in 0..7
    const int l16 = lane & 15, quad = lane >> 4;
    const int b  = blockIdx.z;
    const int nt = blockIdx.x;
    const int n0 = nt * 16;
    const size_t row0 = (size_t)(b * 3) * N_ + (n0 + l16);

    for (int c = t; c < 768; c += 512) {
        int v = c >> 8, rem = c & 255;
        int n = rem >> 4, ch = rem & 15;
        size_t g = (size_t)((b * 3 + v) * N_ + n0 + n) * 128 + ch * 8;
        *(uint4*)(hL + (v * 16 + n) * 128 + ((ch ^ (n & 7)) * 8)) =
            *(const uint4*)(hprev + g);
    }

    if (!FIRST) {
        // (a) pooled means: coalesced element-major read, identical slot order
        if (t < 384) {
            float sum = 0.f;
            const float* p = PpPrev + (size_t)b * 64 * 384 + t;
            #pragma unroll 32
            for (int sl = 0; sl < 64; ++sl) sum += p[(size_t)sl * 384];
            sum *= (1.0f / (float)N_);
            plP[(t % 3) * 128 + (t / 3)] = sum;
        }
        __syncthreads();   // hL staged + plP ready
        // (b) rowadd dots, transposed weights: coalesced over o, serial over c
        if (t < 256) {
            float a0 = 0.f, a1 = 0.f, a2 = 0.f;
            #pragma unroll 16
            for (int c = 0; c < 128; ++c) {
                float w = PW0[(size_t)c * 256 + t];
                a0 += w * plP[c];
                a1 += w * plP[128 + c];
                a2 += w * plP[256 + c];
            }
            plD0[t] = a0; plD0[256 + t] = a1; plD0[512 + t] = a2;
        }
        if (t < 128) {
            float a0 = 0.f, a1 = 0.f, a2 = 0.f;
            #pragma unroll 16
            for (int c = 0; c < 128; ++c) {
                float w = PW1[(size_t)c * 128 + t];
                a0 += w * plP[c];
                a1 += w * plP[128 + c];
                a2 += w * plP[256 + c];
            }
            plWs[t] = a0; plWs[128 + t] = a1; plWs[256 + t] = a2;
        }
    }
    __syncthreads();

    if (FIRST) {
        f4_t facc[3][2];
        #pragma unroll
        for (int v = 0; v < 3; ++v)
            #pragma unroll
            for (int i = 0; i < 2; ++i)
                #pragma unroll
                for (int e = 0; e < 4; ++e) facc[v][i][e] = 0.f;
        const half_t* Af = Wfc + (size_t)(wm * 32 + l16) * 128 + quad * 8;
        #pragma unroll
        for (int k0 = 0; k0 < 128; k0 += 32) {
            h8_t ah[2], bh[3];
            #pragma unroll
            for (int i = 0; i < 2; ++i)
                ah[i] = *(const h8_t*)(Af + (size_t)i * 2048 + k0);
            int lc = (k0 >> 3) + quad;
            #pragma unroll
            for (int v = 0; v < 3; ++v)
                bh[v] = *(const h8_t*)(hL + (v * 16 + l16) * 128 + ((lc ^ (l16 & 7)) * 8));
            #pragma unroll
            for (int v = 0; v < 3; ++v)
                #pragma unroll
                for (int i = 0; i < 2; ++i)
                    facc[v][i] = __builtin_amdgcn_mfma_f32_16x16x32_f16(
                        ah[i], bh[v], facc[v][i], 0, 0, 0);
        }
        __syncthreads();   // all hL reads done before HdL... (HdL disjoint from hL; this also orders hL-dead for later a0L overlay)
        #pragma unroll
        for (int i = 0; i < 2; ++i) {
            int o = wm * 32 + i * 16 + quad * 4;
            #pragma unroll
            for (int v = 0; v < 3; ++v) stsw256(HdL, v, l16, o, facc[v][i]);
        }
        __syncthreads();
    }

    // accS: Ws*hidden accumulator (held to S3); same MFMA order as the old
    // standalone S3 Ws loop -> bit-identical.
    f4_t accS[3];
    #pragma unroll
    for (int v = 0; v < 3; ++v)
        #pragma unroll
        for (int e = 0; e < 4; ++e) accS[v][e] = 0.f;

    // S0 (+Ws fold): a0 = vnrelu(hidden, Wd0*hidden(+addD0)); accS += Ws*hidden
    {
        constexpr int C = FIRST ? 256 : 128;
        f4_t acc[3][2];
        #pragma unroll
        for (int v = 0; v < 3; ++v)
            #pragma unroll
            for (int i = 0; i < 2; ++i)
                #pragma unroll
                for (int e = 0; e < 4; ++e) acc[v][i][e] = 0.f;

        const half_t* Ad  = Wd0 + (size_t)(wm * 32 + l16) * 256 + quad * 8;
        const half_t* AsW = Ws  + (size_t)(wm * 16 + l16) * 256 + quad * 8;
        #pragma unroll
        for (int k0 = 0; k0 < C; k0 += 32) {
            h8_t ah[2], ahs, bh[3];
            #pragma unroll
            for (int i = 0; i < 2; ++i)
                ah[i] = *(const h8_t*)(Ad + (size_t)i * 4096 + k0);
            ahs = *(const h8_t*)(AsW + k0);
            int lc = (k0 >> 3) + quad;
            if (FIRST) {
                #pragma unroll
                for (int v = 0; v < 3; ++v)
                    bh[v] = *(const h8_t*)(HdL + (v * 16 + l16) * 256 + ((lc ^ (l16 & 7)) * 8));
            } else {
                #pragma unroll
                for (int v = 0; v < 3; ++v)
                    bh[v] = *(const h8_t*)(hL + (v * 16 + l16) * 128 + ((lc ^ (l16 & 7)) * 8));
            }
            #pragma unroll
            for (int v = 0; v < 3; ++v) {
                #pragma unroll
                for (int i = 0; i < 2; ++i)
                    acc[v][i] = __builtin_amdgcn_mfma_f32_16x16x32_f16(
                        ah[i], bh[v], acc[v][i], 0, 0, 0);
                accS[v] = __builtin_amdgcn_mfma_f32_16x16x32_f16(
                    ahs, bh[v], accS[v], 0, 0, 0);
            }
        }
        f4_t qs[2][3];
        #pragma unroll
        for (int i = 0; i < 2; ++i) {
            int o = wm * 32 + i * 16 + quad * 4;
            f4_t d[3], p[3];
            #pragma unroll
            for (int v = 0; v < 3; ++v) {
                d[v] = acc[v][i];
                if (!FIRST) {
                    #pragma unroll
                    for (int e = 0; e < 4; ++e) d[v][e] += plD0[v * 256 + o + e];
                }
            }
            if (FIRST) {
                #pragma unroll
                for (int v = 0; v < 3; ++v)
                    p[v] = ldsw256(HdL, v, l16, o);
            } else {
                if (o < 128) {
                    #pragma unroll
                    for (int v = 0; v < 3; ++v)
                        p[v] = ldsw128(hL, v, l16, o);
                } else {
                    #pragma unroll
                    for (int e = 0; e < 4; ++e) {
                        p[0][e] = plP[0 * 128 + o - 128 + e];
                        p[1][e] = plP[1 * 128 + o - 128 + e];
                        p[2][e] = plP[2 * 128 + o - 128 + e];
                    }
                }
            }
            #pragma unroll
            for (int e = 0; e < 4; ++e) {
                float dot = p[0][e] * d[0][e] + p[1][e] * d[1][e] + p[2][e] * d[2][e];
                float dsq = d[0][e] * d[0][e] + d[1][e] * d[1][e] + d[2][e] * d[2][e] + EPS_;
                float cf = dot / dsq;
                if (dot >= 0.f) {
                    qs[i][0][e] = p[0][e]; qs[i][1][e] = p[1][e]; qs[i][2][e] = p[2][e];
                } else {
                    qs[i][0][e] = p[0][e] - cf * d[0][e];
                    qs[i][1][e] = p[1][e] - cf * d[1][e];
                    qs[i][2][e] = p[2][e] - cf * d[2][e];
                }
            }
            if (FIRST) {   // a0L overlays dead hL only -> store directly
                #pragma unroll
                for (int v = 0; v < 3; ++v) stsw256(a0L, v, l16, o, qs[i][v]);
            }
        }
        if (!FIRST) {
            __syncthreads();   // all plP/plD0 reads done before a0L overwrite
            #pragma unroll
            for (int i = 0; i < 2; ++i) {
                int o = wm * 32 + i * 16 + quad * 4;
                #pragma unroll
                for (int v = 0; v < 3; ++v) stsw256(a0L, v, l16, o, qs[i][v]);
            }
        }
    }
    __syncthreads();

    // S1: net = W0 * a0
    f4_t acc1[3];
    #pragma unroll
    for (int v = 0; v < 3; ++v)
        #pragma unroll
        for (int e = 0; e < 4; ++e) acc1[v][e] = 0.f;

    {
        const half_t* Aw = W0 + (size_t)(wm * 16 + l16) * 256 + quad * 8;
        #pragma unroll
        for (int k0 = 0; k0 < 256; k0 += 32) {
            h8_t ah, bh[3];
            ah = *(const h8_t*)(Aw + k0);
            int lc = (k0 >> 3) + quad;
            #pragma unroll
            for (int v = 0; v < 3; ++v)
                bh[v] = *(const h8_t*)(a0L + (v * 16 + l16) * 256 + ((lc ^ (l16 & 7)) * 8));
            #pragma unroll
            for (int v = 0; v < 3; ++v)
                acc1[v] = __builtin_amdgcn_mfma_f32_16x16x32_f16(ah, bh[v], acc1[v], 0, 0, 0);
        }
    }
    __syncthreads();   // a0L reads done; (FIRST: netL overlays dead HdL)
    {
        int o = wm * 16 + quad * 4;
        #pragma unroll
        for (int v = 0; v < 3; ++v) stsw128(netL, v, l16, o, acc1[v]);
    }
    __syncthreads();

    // S2: a1 = vnrelu(net, Wd1*net)
    #pragma unroll
    for (int v = 0; v < 3; ++v)
        #pragma unroll
        for (int e = 0; e < 4; ++e) acc1[v][e] = 0.f;

    {
        const half_t* Ad1 = Wd1 + (size_t)(wm * 16 + l16) * 128 + quad * 8;
        #pragma unroll
        for (int k0 = 0; k0 < 128; k0 += 32) {
            h8_t ah, bh[3];
            ah = *(const h8_t*)(Ad1 + k0);
            int lc = (k0 >> 3) + quad;
            #pragma unroll
            for (int v = 0; v < 3; ++v)
                bh[v] = *(const h8_t*)(netL + (v * 16 + l16) * 128 + ((lc ^ (l16 & 7)) * 8));
            #pragma unroll
            for (int v = 0; v < 3; ++v)
                acc1[v] = __builtin_amdgcn_mfma_f32_16x16x32_f16(ah, bh[v], acc1[v], 0, 0, 0);
        }
    }
    {
        int o = wm * 16 + quad * 4;
        f4_t p[3], q[3];
        #pragma unroll
        for (int v = 0; v < 3; ++v) p[v] = ldsw128(netL, v, l16, o);
        #pragma unroll
        for (int e = 0; e < 4; ++e) {
            float dot = p[0][e] * acc1[0][e] + p[1][e] * acc1[1][e] + p[2][e] * acc1[2][e];
            float dsq = acc1[0][e] * acc1[0][e] + acc1[1][e] * acc1[1][e]
                      + acc1[2][e] * acc1[2][e] + EPS_;
            float cf = dot / dsq;
            if (dot >= 0.f) { q[0][e] = p[0][e]; q[1][e] = p[1][e]; q[2][e] = p[2][e]; }
            else {
                q[0][e] = p[0][e] - cf * acc1[0][e];
                q[1][e] = p[1][e] - cf * acc1[1][e];
                q[2][e] = p[2][e] - cf * acc1[2][e];
            }
        }
        #pragma unroll
        for (int v = 0; v < 3; ++v) stsw128(a1L, v, l16, o, q[v]);
    }
    __syncthreads();

    // S3: h = accS (Ws*hidden, already accumulated) + W1*a1 (+addWs)
    #pragma unroll
    for (int v = 0; v < 3; ++v) acc1[v] = accS[v];

    {
        const half_t* A1 = W1 + (size_t)(wm * 16 + l16) * 128 + quad * 8;
        #pragma unroll
        for (int k0 = 0; k0 < 128; k0 += 32) {
            h8_t ah, bh[3];
            ah = *(const h8_t*)(A1 + k0);
            int lc = (k0 >> 3) + quad;
            #pragma unroll
            for (int v = 0; v < 3; ++v)
                bh[v] = *(const h8_t*)(a1L + (v * 16 + l16) * 128 + ((lc ^ (l16 & 7)) * 8));
            #pragma unroll
            for (int v = 0; v < 3; ++v)
                acc1[v] = __builtin_amdgcn_mfma_f32_16x16x32_f16(ah, bh[v], acc1[v], 0, 0, 0);
        }
    }

    const size_t slot = (size_t)b * 64 + nt;
    {
        int o = wm * 16 + quad * 4;
        f4_t d[3];
        #pragma unroll
        for (int v = 0; v < 3; ++v) {
            d[v] = acc1[v];
            if (!FIRST) {
                #pragma unroll
                for (int e = 0; e < 4; ++e) d[v][e] += plWs[v * 128 + o + e];
            }
            if (WRITE_OUT)
                st4h(outH, (row0 + (size_t)v * N_) * 128 + o, d[v]);
        }
        #pragma unroll
        for (int v = 0; v < 3; ++v)
            #pragma unroll
            for (int e = 0; e < 4; ++e) {
                float s = d[v][e];
                s += __shfl_xor(s, 1);
                s += __shfl_xor(s, 2);
                s += __shfl_xor(s, 4);
                s += __shfl_xor(s, 8);
                d[v][e] = s;
            }
        if (l16 == 0) {
            #pragma unroll
            for (int v = 0; v < 3; ++v)
                #pragma unroll
                for (int e = 0; e < 4; ++e)
                    PpOut[slot * 384 + (size_t)(o + e) * 3 + v] = d[v][e];
        }
    }
}

// ---------------------------------------------------------------------------
// Final pool + final stage fused (fp32, exact; standalone, reads prev dispatch).
// ---------------------------------------------------------------------------
__global__ __launch_bounds__(128) void pool_final(const float* __restrict__ Pp,
                                                  const float* __restrict__ Wd,
                                                  const float* __restrict__ Wc,
                                                  float* __restrict__ out) {
    int b = blockIdx.x;
    int t = threadIdx.x;
    __shared__ float hid[H_][3];
    __shared__ float act[H_][3];
    {
        float s0 = 0.f, s1 = 0.f, s2 = 0.f;
        const float* p = Pp + (size_t)b * 64 * 384 + (size_t)t * 3;
        #pragma unroll 8
        for (int sl = 0; sl < 64; ++sl) {
            const float* q = p + (size_t)sl * 384;
            s0 += q[0]; s1 += q[1]; s2 += q[2];
        }
        const float inv = 1.0f / (float)N_;
        hid[t][0] = s0 * inv; hid[t][1] = s1 * inv; hid[t][2] = s2 * inv;
    }
    __syncthreads();

    float d0 = 0.f, d1 = 0.f, d2 = 0.f;
    const float* wd = Wd + (size_t)t * H_;
    for (int c = 0; c < H_; ++c) {
        float w = wd[c];
        d0 += w * hid[c][0]; d1 += w * hid[c][1]; d2 += w * hid[c][2];
    }
    float p0 = hid[t][0], p1 = hid[t][1], p2 = hid[t][2];
    float dot = p0 * d0 + p1 * d1 + p2 * d2;
    float dsq = d0 * d0 + d1 * d1 + d2 * d2 + EPS_;
    float cf = dot / dsq;
    float q0, q1, q2;
    if (dot >= 0.f) { q0 = p0; q1 = p1; q2 = p2; }
    else            { q0 = p0 - cf * d0; q1 = p1 - cf * d1; q2 = p2 - cf * d2; }
    act[t][0] = 0.2f * p0 + 0.8f * q0;
    act[t][1] = 0.2f * p1 + 0.8f * q1;
    act[t][2] = 0.2f * p2 + 0.8f * q2;
    __syncthreads();

    float o0 = 0.f, o1 = 0.f, o2 = 0.f;
    const float* wc = Wc + (size_t)t * H_;
    for (int c = 0; c < H_; ++c) {
        float w = wc[c];
        o0 += w * act[c][0]; o1 += w * act[c][1]; o2 += w * act[c][2];
    }
    size_t ob = ((size_t)b * H_ + t) * 3;
    out[ob + 0] = o0; out[ob + 1] = o1; out[ob + 2] = o2;
}

// ---------------------------------------------------------------------------
extern "C" void kernel_launch(void* const* d_in, const int* in_sizes, int n_in,
                              void* d_out, int out_size, void* d_ws, size_t ws_size,
                              hipStream_t stream) {
    const float* x   = (const float*)d_in[0];
    const float* Wf  = (const float*)d_in[1];
    const float* Wdp = (const float*)d_in[2];
    const float* Wfc = (const float*)d_in[3];
    const float* Wd0 = (const float*)d_in[4];
    const float* W0  = (const float*)d_in[5];
    const float* Wd1 = (const float*)d_in[6];
    const float* W1  = (const float*)d_in[7];
    const float* Wsc = (const float*)d_in[8];
    const float* Wda = (const float*)d_in[9];
    const float* Wc  = (const float*)d_in[10];
    float* out = (float*)d_out;
    (void)in_sizes; (void)n_in; (void)out_size; (void)ws_size;

    char* ws = (char*)d_ws;
    size_t off = 0;
    auto alloc = [&](size_t bytes) {
        void* p = ws + off;
        off = (off + bytes + 255) & ~(size_t)255;
        return p;
    };
    const size_t e128 = (size_t)R_ * 128;
    const size_t ppSl = (size_t)B_ * 64 * 384;
    half_t* wAll  = (half_t*)alloc((size_t)W_TOT * 2);
    half_t* h1F   = (half_t*)alloc(e128 * 2);
    half_t* hF[2] = { (half_t*)alloc(e128 * 2), (half_t*)alloc(e128 * 2) };
    float*  Pp    = (float*) alloc(4 * ppSl * 4);
    float*  WD0T  = (float*) alloc((size_t)TRD_TOT * 4);
    float*  WST   = (float*) alloc((size_t)TRS_TOT * 4);

    const half_t* whFc = wAll + OFF_FC;
    const half_t* whD0 = wAll + OFF_D0;
    const half_t* whW0 = wAll + OFF_W0;
    const half_t* whD1 = wAll + OFF_D1;
    const half_t* whW1 = wAll + OFF_W1;
    const half_t* whWs = wAll + OFF_WS;

    hipLaunchKernelGGL(prep, dim3(KNN_BLKS + CVT_BLKS + TR_BLKS), dim3(256), 0, stream,
                       x, Wf, Wdp, h1F, Wfc, Wd0, W0, Wd1, W1, Wsc, wAll, WD0T, WST);

    for (int i = 0; i < 4; ++i) {
        int cur = i & 1, prv = cur ^ 1;
        if (i == 0) {
            block_full<true, true><<<dim3(64, 1, 8), 512, 0, stream>>>(
                whFc, whD0, whW0, whD1, whWs, whW1,
                h1F, nullptr, nullptr, nullptr, hF[cur], Pp);
        } else if (i < 3) {
            block_full<false, true><<<dim3(64, 1, 8), 512, 0, stream>>>(
                whFc, whD0 + (size_t)i * 65536, whW0 + (size_t)i * 32768,
                whD1 + (size_t)i * 16384, whWs + (size_t)i * 32768,
                whW1 + (size_t)i * 16384,
                hF[prv], Pp + (size_t)(i - 1) * ppSl,
                WD0T + (size_t)(i - 1) * 32768, WST + (size_t)(i - 1) * 16384,
                hF[cur], Pp + (size_t)i * ppSl);
        } else {
            block_full<false, false><<<dim3(64, 1, 8), 512, 0, stream>>>(
                whFc, whD0 + (size_t)i * 65536, whW0 + (size_t)i * 32768,
                whD1 + (size_t)i * 16384, whWs + (size_t)i * 32768,
                whW1 + (size_t)i * 16384,
                hF[prv], Pp + (size_t)(i - 1) * ppSl,
                WD0T + (size_t)(i - 1) * 32768, WST + (size_t)(i - 1) * 16384,
                nullptr, Pp + (size_t)i * ppSl);
        }
    }
    hipLaunchKernelGGL(pool_final, dim3(B_), dim3(128), 0, stream,
                       Pp + (size_t)3 * ppSl, Wda, Wc, out);
}

// Round 12
// 210.935 us; speedup vs baseline: 1.0303x; 1.0303x over previous
//
#include <hip/hip_runtime.h>
#include <cfloat>
#include <cstdint>

#define B_   8
#define N_   1024
#define H_   128
#define K_   20
#define EPS_ 1e-6f
#define R_   (B_ * 3 * N_)

typedef _Float16 half_t;
typedef _Float16 h8_t __attribute__((ext_vector_type(8)));
typedef _Float16 h4_t __attribute__((ext_vector_type(4)));
typedef __attribute__((ext_vector_type(4))) float f4_t;

__device__ inline void st4h(half_t* __restrict__ p, size_t off, f4_t v) {
    h4_t o;
    o[0] = (half_t)v[0]; o[1] = (half_t)v[1]; o[2] = (half_t)v[2]; o[3] = (half_t)v[3];
    *(h4_t*)(p + off) = o;
}

#define OFF_FC 0
#define OFF_D0 32768
#define OFF_W0 294912
#define OFF_D1 425984
#define OFF_W1 491520
#define OFF_WS 557056
#define W_TOT  688128
#define KNN_BLKS (B_ * N_ / 4)
#define CVT_BLKS ((W_TOT + 255) / 256)
#define TRD_TOT  98304   /* 3 layers x 128 x 256 */
#define TRS_TOT  49152   /* 3 layers x 128 x 128 */
#define TR_BLKS  ((TRD_TOT + TRS_TOT) / 256)

// ---------------------------------------------------------------------------
// prep (R12 = R10 version, attribution revert): DPP selection + SEPARATE
// conv loop over stored opw (ILP-rich; proven in the 236->212 round).
// R11's conv-fusion serialized conv behind the selection chain -> reverted.
// ---------------------------------------------------------------------------
__global__ __launch_bounds__(256) void prep(const float* __restrict__ x,
                                            const float* __restrict__ Wf,
                                            const float* __restrict__ Wd,
                                            half_t* __restrict__ h1,
                                            const float* __restrict__ Wfc,
                                            const float* __restrict__ Wd0,
                                            const float* __restrict__ W0,
                                            const float* __restrict__ Wd1,
                                            const float* __restrict__ W1,
                                            const float* __restrict__ Wsc,
                                            half_t* __restrict__ w,
                                            float* __restrict__ wd0t,
                                            float* __restrict__ wst) {
    __shared__ float ps[N_ * 3];
    __shared__ int opw[4][K_];
    int t = threadIdx.x;

    if (blockIdx.x >= KNN_BLKS + CVT_BLKS) {
        int j = (blockIdx.x - KNN_BLKS - CVT_BLKS) * 256 + t;
        if (j < TRD_TOT) {
            int L = j >> 15, rem = j & 32767;
            int c = rem >> 8, o = rem & 255;
            wd0t[j] = Wd0[(size_t)(L + 1) * 65536 + o * 256 + 128 + c];
        } else {
            int k = j - TRD_TOT;
            int L = k >> 14, rem = k & 16383;
            int c = rem >> 7, o = rem & 127;
            wst[k] = Wsc[(size_t)(L + 1) * 32768 + o * 256 + 128 + c];
        }
        return;
    }
    if (blockIdx.x >= KNN_BLKS) {
        int bid = blockIdx.x - KNN_BLKS;
        int i = bid * 256 + t;
        if (i < W_TOT) {
            const float* src; int off;
            if (i < OFF_W0)      { if (i < OFF_D0) { src = Wfc; off = OFF_FC; }
                                   else            { src = Wd0; off = OFF_D0; } }
            else if (i < OFF_W1) { if (i < OFF_D1) { src = W0;  off = OFF_W0; }
                                   else            { src = Wd1; off = OFF_D1; } }
            else                 { if (i < OFF_WS) { src = W1;  off = OFF_W1; }
                                   else            { src = Wsc; off = OFF_WS; } }
            w[i] = (half_t)src[i - off];
        }
        return;
    }

    int wv = t >> 6, lane = t & 63;
    int b = blockIdx.x >> 8;
    int n = (blockIdx.x & 255) * 4 + wv;

    const float4* xb4 = (const float4*)(x + (size_t)b * N_ * 3);
    float4* ps4 = (float4*)ps;
    #pragma unroll
    for (int i = 0; i < 3; ++i) ps4[t + i * 256] = xb4[t + i * 256];
    __syncthreads();

    const float cx = ps[3 * n + 0], cy = ps[3 * n + 1], cz = ps[3 * n + 2];
    uint ku[16];
    #pragma unroll
    for (int k = 0; k < 16; ++k) {
        int j = lane + (k << 6);
        const float* pj = ps + 3 * j;
        float dx = pj[0] - cx, dy = pj[1] - cy, dz = pj[2] - cz;
        float d = fmaf(dz, dz, fmaf(dy, dy, dx * dx));
        ku[k] = (__float_as_uint(d) & 0xFFFFFC00u) | (uint)j;
    }
    for (int s = 0; s < K_; ++s) {
        uint a0 = min(min(ku[0],  ku[1]),  ku[2]);
        uint a1 = min(min(ku[3],  ku[4]),  ku[5]);
        uint a2 = min(min(ku[6],  ku[7]),  ku[8]);
        uint a3 = min(min(ku[9],  ku[10]), ku[11]);
        uint a4 = min(min(ku[12], ku[13]), ku[14]);
        uint m  = min(min(min(a0, a1), min(a2, a3)), min(a4, ku[15]));
        // 16-lane row min via DPP row_ror (no DS latency)
        m = min(m, (uint)__builtin_amdgcn_update_dpp(0, (int)m, 0x121, 0xF, 0xF, true));
        m = min(m, (uint)__builtin_amdgcn_update_dpp(0, (int)m, 0x122, 0xF, 0xF, true));
        m = min(m, (uint)__builtin_amdgcn_update_dpp(0, (int)m, 0x124, 0xF, 0xF, true));
        m = min(m, (uint)__builtin_amdgcn_update_dpp(0, (int)m, 0x128, 0xF, 0xF, true));
        uint mm = min(min((uint)__builtin_amdgcn_readlane((int)m, 0),
                          (uint)__builtin_amdgcn_readlane((int)m, 16)),
                      min((uint)__builtin_amdgcn_readlane((int)m, 32),
                          (uint)__builtin_amdgcn_readlane((int)m, 48)));
        int j = (int)(mm & 1023u);
        if ((j & 63) == lane) {
            opw[wv][s] = j;
            ku[j >> 6] = 0xFFFFFFFFu;
        }
    }
    __syncthreads();

    float wf0[2], wf2[2], wd0c[2], wd2c[2];
    float bf[2][3], bg[2][3];
    #pragma unroll
    for (int c = 0; c < 2; ++c) {
        int ch = lane + c * 64;
        wf0[c]  = Wf[ch * 3 + 0];
        float wf1 = Wf[ch * 3 + 1];
        wf2[c]  = Wf[ch * 3 + 2];
        wd0c[c] = Wd[ch * 3 + 0];
        float wd1 = Wd[ch * 3 + 1];
        wd2c[c] = Wd[ch * 3 + 2];
        float df = wf1 - wf0[c], dg = wd1 - wd0c[c];
        bf[c][0] = df * cx; bf[c][1] = df * cy; bf[c][2] = df * cz;
        bg[c][0] = dg * cx; bg[c][1] = dg * cy; bg[c][2] = dg * cz;
    }
    float ax[2] = {0.f, 0.f}, ay[2] = {0.f, 0.f}, az[2] = {0.f, 0.f};
    for (int k = 0; k < K_; ++k) {
        int j = opw[wv][k];
        const float* pj = ps + 3 * j;
        float nx = pj[0], ny = pj[1], nz = pj[2];
        float rx = fmaf(ny, cz, -(nz * cy));
        float ry = fmaf(nz, cx, -(nx * cz));
        float rz = fmaf(nx, cy, -(ny * cx));
        #pragma unroll
        for (int c = 0; c < 2; ++c) {
            float fx = fmaf(wf0[c], nx, fmaf(wf2[c], rx, bf[c][0]));
            float fy = fmaf(wf0[c], ny, fmaf(wf2[c], ry, bf[c][1]));
            float fz = fmaf(wf0[c], nz, fmaf(wf2[c], rz, bf[c][2]));
            float gx = fmaf(wd0c[c], nx, fmaf(wd2c[c], rx, bg[c][0]));
            float gy = fmaf(wd0c[c], ny, fmaf(wd2c[c], ry, bg[c][1]));
            float gz = fmaf(wd0c[c], nz, fmaf(wd2c[c], rz, bg[c][2]));
            float dot = fmaf(fz, gz, fmaf(fy, gy, fx * gx));
            float dsq = fmaf(gz, gz, fmaf(gy, gy, fmaf(gx, gx, EPS_)));
            float u = fminf(dot, 0.f) * __builtin_amdgcn_rcpf(dsq) * -0.8f;
            ax[c] = fmaf(u, gx, ax[c] + fx);
            ay[c] = fmaf(u, gy, ay[c] + fy);
            az[c] = fmaf(u, gz, az[c] + fz);
        }
    }
    const float inv = 1.0f / (float)K_;
    size_t r0 = ((size_t)b * 3) * N_ + n;
    #pragma unroll
    for (int c = 0; c < 2; ++c) {
        int ch = lane + c * 64;
        h1[(r0) * H_ + ch]          = (half_t)(ax[c] * inv);
        h1[(r0 + N_) * H_ + ch]     = (half_t)(ay[c] * inv);
        h1[(r0 + 2 * N_) * H_ + ch] = (half_t)(az[c] * inv);
    }
}

// ---------------------------------------------------------------------------
// Swizzled LDS helpers.
// ---------------------------------------------------------------------------
__device__ inline void stsw128(half_t* __restrict__ buf, int v, int n, int o, f4_t val) {
    int phys = (((o >> 3) ^ (n & 7)) * 8) + (o & 7);
    half_t* p = buf + (v * 16 + n) * 128 + phys;
    h4_t h;
    h[0] = (half_t)val[0]; h[1] = (half_t)val[1];
    h[2] = (half_t)val[2]; h[3] = (half_t)val[3];
    *(h4_t*)p = h;
}
__device__ inline f4_t ldsw128(const half_t* __restrict__ buf, int v, int n, int o) {
    int phys = (((o >> 3) ^ (n & 7)) * 8) + (o & 7);
    const half_t* p = buf + (v * 16 + n) * 128 + phys;
    h4_t x = *(const h4_t*)p;
    f4_t r;
    r[0] = (float)x[0]; r[1] = (float)x[1]; r[2] = (float)x[2]; r[3] = (float)x[3];
    return r;
}
__device__ inline void stsw256(half_t* __restrict__ buf, int v, int n, int o, f4_t val) {
    int phys = (((o >> 3) ^ (n & 7)) * 8) + (o & 7);
    half_t* p = buf + (v * 16 + n) * 256 + phys;
    h4_t h;
    h[0] = (half_t)val[0]; h[1] = (half_t)val[1];
    h[2] = (half_t)val[2]; h[3] = (half_t)val[3];
    *(h4_t*)p = h;
}
__device__ inline f4_t ldsw256(const half_t* __restrict__ buf, int v, int n, int o) {
    int phys = (((o >> 3) ^ (n & 7)) * 8) + (o & 7);
    const half_t* p = buf + (v * 16 + n) * 256 + phys;
    h4_t x = *(const h4_t*)p;
    f4_t r;
    r[0] = (float)x[0]; r[1] = (float)x[1]; r[2] = (float)x[2]; r[3] = (float)x[3];
    return r;
}

// ---------------------------------------------------------------------------
// block_full (R12 = R11 version): compact FIRST LDS (49152B => 3 blk/CU,
// HdL dead after S0 since the R9 Ws-fold), R10 prologue unrolls.
// ---------------------------------------------------------------------------
template<bool FIRST, bool WRITE_OUT>
__global__ __launch_bounds__(512) void block_full(const half_t* __restrict__ Wfc,
                                                  const half_t* __restrict__ Wd0,
                                                  const half_t* __restrict__ W0,
                                                  const half_t* __restrict__ Wd1,
                                                  const half_t* __restrict__ Ws,
                                                  const half_t* __restrict__ W1,
                                                  const half_t* __restrict__ hprev,
                                                  const float* __restrict__ PpPrev,
                                                  const float* __restrict__ PW0,
                                                  const float* __restrict__ PW1,
                                                  half_t* __restrict__ outH,
                                                  float* __restrict__ PpOut) {
    __shared__ __align__(16) char smem[FIRST ? 49152 : 50688];
    half_t* hL   = (half_t*)(FIRST ? smem + 24576 : smem);
    half_t* HdL  = (half_t*)(smem);                               // FIRST only
    half_t* a0L  = (half_t*)(FIRST ? smem + 24576 : smem + 12288);
    half_t* netL = (half_t*)(FIRST ? smem : smem + 36864);
    half_t* a1L  = (half_t*)(FIRST ? smem + 12288 : smem + 24576);
    float* plP  = (float*)(smem + 12288);          // [3][128] (non-FIRST prologue)
    float* plD0 = (float*)(smem + 12288 + 1536);   // [3][256]
    float* plWs = (float*)(FIRST ? smem : smem + 49152); // unused for FIRST

    const int t = threadIdx.x;
    const int lane = t & 63, wm = t >> 6;            // wm in 0..7
    const int l16 = lane & 15, quad = lane >> 4;
    const int b  = blockIdx.z;
    const int nt = blockIdx.x;
    const int n0 = nt * 16;
    const size_t row0 = (size_t)(b * 3) * N_ + (n0 + l16);

    for (int c = t; c < 768; c += 512) {
        int v = c >> 8, rem = c & 255;
        int n = rem >> 4, ch = rem & 15;
        size_t g = (size_t)((b * 3 + v) * N_ + n0 + n) * 128 + ch * 8;
        *(uint4*)(hL + (v * 16 + n) * 128 + ((ch ^ (n & 7)) * 8)) =
            *(const uint4*)(hprev + g);
    }

    if (!FIRST) {
        // (a) pooled means: coalesced element-major read, identical slot order
        if (t < 384) {
            float sum = 0.f;
            const float* p = PpPrev + (size_t)b * 64 * 384 + t;
            #pragma unroll 32
            for (int sl = 0; sl < 64; ++sl) sum += p[(size_t)sl * 384];
            sum *= (1.0f / (float)N_);
            plP[(t % 3) * 128 + (t / 3)] = sum;
        }
        __syncthreads();   // hL staged + plP ready
        // (b) rowadd dots, transposed weights: coalesced over o, serial over c
        if (t < 256) {
            float a0 = 0.f, a1 = 0.f, a2 = 0.f;
            #pragma unroll 16
            for (int c = 0; c < 128; ++c) {
                float w = PW0[(size_t)c * 256 + t];
                a0 += w * plP[c];
                a1 += w * plP[128 + c];
                a2 += w * plP[256 + c];
            }
            plD0[t] = a0; plD0[256 + t] = a1; plD0[512 + t] = a2;
        }
        if (t < 128) {
            float a0 = 0.f, a1 = 0.f, a2 = 0.f;
            #pragma unroll 16
            for (int c = 0; c < 128; ++c) {
                float w = PW1[(size_t)c * 128 + t];
                a0 += w * plP[c];
                a1 += w * plP[128 + c];
                a2 += w * plP[256 + c];
            }
            plWs[t] = a0; plWs[128 + t] = a1; plWs[256 + t] = a2;
        }
    }
    __syncthreads();

    if (FIRST) {
        f4_t facc[3][2];
        #pragma unroll
        for (int v = 0; v < 3; ++v)
            #pragma unroll
            for (int i = 0; i < 2; ++i)
                #pragma unroll
                for (int e = 0; e < 4; ++e) facc[v][i][e] = 0.f;
        const half_t* Af = Wfc + (size_t)(wm * 32 + l16) * 128 + quad * 8;
        #pragma unroll
        for (int k0 = 0; k0 < 128; k0 += 32) {
            h8_t ah[2], bh[3];
            #pragma unroll
            for (int i = 0; i < 2; ++i)
                ah[i] = *(const h8_t*)(Af + (size_t)i * 2048 + k0);
            int lc = (k0 >> 3) + quad;
            #pragma unroll
            for (int v = 0; v < 3; ++v)
                bh[v] = *(const h8_t*)(hL + (v * 16 + l16) * 128 + ((lc ^ (l16 & 7)) * 8));
            #pragma unroll
            for (int v = 0; v < 3; ++v)
                #pragma unroll
                for (int i = 0; i < 2; ++i)
                    facc[v][i] = __builtin_amdgcn_mfma_f32_16x16x32_f16(
                        ah[i], bh[v], facc[v][i], 0, 0, 0);
        }
        __syncthreads();   // all hL reads done (hL dead hereafter; a0L overlays it)
        #pragma unroll
        for (int i = 0; i < 2; ++i) {
            int o = wm * 32 + i * 16 + quad * 4;
            #pragma unroll
            for (int v = 0; v < 3; ++v) stsw256(HdL, v, l16, o, facc[v][i]);
        }
        __syncthreads();
    }

    // accS: Ws*hidden accumulator (held to S3); same MFMA order as the old
    // standalone S3 Ws loop -> bit-identical.
    f4_t accS[3];
    #pragma unroll
    for (int v = 0; v < 3; ++v)
        #pragma unroll
        for (int e = 0; e < 4; ++e) accS[v][e] = 0.f;

    // S0 (+Ws fold): a0 = vnrelu(hidden, Wd0*hidden(+addD0)); accS += Ws*hidden
    {
        constexpr int C = FIRST ? 256 : 128;
        f4_t acc[3][2];
        #pragma unroll
        for (int v = 0; v < 3; ++v)
            #pragma unroll
            for (int i = 0; i < 2; ++i)
                #pragma unroll
                for (int e = 0; e < 4; ++e) acc[v][i][e] = 0.f;

        const half_t* Ad  = Wd0 + (size_t)(wm * 32 + l16) * 256 + quad * 8;
        const half_t* AsW = Ws  + (size_t)(wm * 16 + l16) * 256 + quad * 8;
        #pragma unroll
        for (int k0 = 0; k0 < C; k0 += 32) {
            h8_t ah[2], ahs, bh[3];
            #pragma unroll
            for (int i = 0; i < 2; ++i)
                ah[i] = *(const h8_t*)(Ad + (size_t)i * 4096 + k0);
            ahs = *(const h8_t*)(AsW + k0);
            int lc = (k0 >> 3) + quad;
            if (FIRST) {
                #pragma unroll
                for (int v = 0; v < 3; ++v)
                    bh[v] = *(const h8_t*)(HdL + (v * 16 + l16) * 256 + ((lc ^ (l16 & 7)) * 8));
            } else {
                #pragma unroll
                for (int v = 0; v < 3; ++v)
                    bh[v] = *(const h8_t*)(hL + (v * 16 + l16) * 128 + ((lc ^ (l16 & 7)) * 8));
            }
            #pragma unroll
            for (int v = 0; v < 3; ++v) {
                #pragma unroll
                for (int i = 0; i < 2; ++i)
                    acc[v][i] = __builtin_amdgcn_mfma_f32_16x16x32_f16(
                        ah[i], bh[v], acc[v][i], 0, 0, 0);
                accS[v] = __builtin_amdgcn_mfma_f32_16x16x32_f16(
                    ahs, bh[v], accS[v], 0, 0, 0);
            }
        }
        f4_t qs[2][3];
        #pragma unroll
        for (int i = 0; i < 2; ++i) {
            int o = wm * 32 + i * 16 + quad * 4;
            f4_t d[3], p[3];
            #pragma unroll
            for (int v = 0; v < 3; ++v) {
                d[v] = acc[v][i];
                if (!FIRST) {
                    #pragma unroll
                    for (int e = 0; e < 4; ++e) d[v][e] += plD0[v * 256 + o + e];
                }
            }
            if (FIRST) {
                #pragma unroll
                for (int v = 0; v < 3; ++v)
                    p[v] = ldsw256(HdL, v, l16, o);
            } else {
                if (o < 128) {
                    #pragma unroll
                    for (int v = 0; v < 3; ++v)
                        p[v] = ldsw128(hL, v, l16, o);
                } else {
                    #pragma unroll
                    for (int e = 0; e < 4; ++e) {
                        p[0][e] = plP[0 * 128 + o - 128 + e];
                        p[1][e] = plP[1 * 128 + o - 128 + e];
                        p[2][e] = plP[2 * 128 + o - 128 + e];
                    }
                }
            }
            #pragma unroll
            for (int e = 0; e < 4; ++e) {
                float dot = p[0][e] * d[0][e] + p[1][e] * d[1][e] + p[2][e] * d[2][e];
                float dsq = d[0][e] * d[0][e] + d[1][e] * d[1][e] + d[2][e] * d[2][e] + EPS_;
                float cf = dot / dsq;
                if (dot >= 0.f) {
                    qs[i][0][e] = p[0][e]; qs[i][1][e] = p[1][e]; qs[i][2][e] = p[2][e];
                } else {
                    qs[i][0][e] = p[0][e] - cf * d[0][e];
                    qs[i][1][e] = p[1][e] - cf * d[1][e];
                    qs[i][2][e] = p[2][e] - cf * d[2][e];
                }
            }
            if (FIRST) {   // a0L overlays dead hL only -> store directly
                #pragma unroll
                for (int v = 0; v < 3; ++v) stsw256(a0L, v, l16, o, qs[i][v]);
            }
        }
        if (!FIRST) {
            __syncthreads();   // all plP/plD0 reads done before a0L overwrite
            #pragma unroll
            for (int i = 0; i < 2; ++i) {
                int o = wm * 32 + i * 16 + quad * 4;
                #pragma unroll
                for (int v = 0; v < 3; ++v) stsw256(a0L, v, l16, o, qs[i][v]);
            }
        }
    }
    __syncthreads();

    // S1: net = W0 * a0
    f4_t acc1[3];
    #pragma unroll
    for (int v = 0; v < 3; ++v)
        #pragma unroll
        for (int e = 0; e < 4; ++e) acc1[v][e] = 0.f;

    {
        const half_t* Aw = W0 + (size_t)(wm * 16 + l16) * 256 + quad * 8;
        #pragma unroll
        for (int k0 = 0; k0 < 256; k0 += 32) {
            h8_t ah, bh[3];
            ah = *(const h8_t*)(Aw + k0);
            int lc = (k0 >> 3) + quad;
            #pragma unroll
            for (int v = 0; v < 3; ++v)
                bh[v] = *(const h8_t*)(a0L + (v * 16 + l16) * 256 + ((lc ^ (l16 & 7)) * 8));
            #pragma unroll
            for (int v = 0; v < 3; ++v)
                acc1[v] = __builtin_amdgcn_mfma_f32_16x16x32_f16(ah, bh[v], acc1[v], 0, 0, 0);
        }
    }
    __syncthreads();   // a0L reads done; (FIRST: netL overlays dead HdL)
    {
        int o = wm * 16 + quad * 4;
        #pragma unroll
        for (int v = 0; v < 3; ++v) stsw128(netL, v, l16, o, acc1[v]);
    }
    __syncthreads();

    // S2: a1 = vnrelu(net, Wd1*net)
    #pragma unroll
    for (int v = 0; v < 3; ++v)
        #pragma unroll
        for (int e = 0; e < 4; ++e) acc1[v][e] = 0.f;

    {
        const half_t* Ad1 = Wd1 + (size_t)(wm * 16 + l16) * 128 + quad * 8;
        #pragma unroll
        for (int k0 = 0; k0 < 128; k0 += 32) {
            h8_t ah, bh[3];
            ah = *(const h8_t*)(Ad1 + k0);
            int lc = (k0 >> 3) + quad;
            #pragma unroll
            for (int v = 0; v < 3; ++v)
                bh[v] = *(const h8_t*)(netL + (v * 16 + l16) * 128 + ((lc ^ (l16 & 7)) * 8));
            #pragma unroll
            for (int v = 0; v < 3; ++v)
                acc1[v] = __builtin_amdgcn_mfma_f32_16x16x32_f16(ah, bh[v], acc1[v], 0, 0, 0);
        }
    }
    {
        int o = wm * 16 + quad * 4;
        f4_t p[3], q[3];
        #pragma unroll
        for (int v = 0; v < 3; ++v) p[v] = ldsw128(netL, v, l16, o);
        #pragma unroll
        for (int e = 0; e < 4; ++e) {
            float dot = p[0][e] * acc1[0][e] + p[1][e] * acc1[1][e] + p[2][e] * acc1[2][e];
            float dsq = acc1[0][e] * acc1[0][e] + acc1[1][e] * acc1[1][e]
                      + acc1[2][e] * acc1[2][e] + EPS_;
            float cf = dot / dsq;
            if (dot >= 0.f) { q[0][e] = p[0][e]; q[1][e] = p[1][e]; q[2][e] = p[2][e]; }
            else {
                q[0][e] = p[0][e] - cf * acc1[0][e];
                q[1][e] = p[1][e] - cf * acc1[1][e];
                q[2][e] = p[2][e] - cf * acc1[2][e];
            }
        }
        #pragma unroll
        for (int v = 0; v < 3; ++v) stsw128(a1L, v, l16, o, q[v]);
    }
    __syncthreads();

    // S3: h = accS (Ws*hidden, already accumulated) + W1*a1 (+addWs)
    #pragma unroll
    for (int v = 0; v < 3; ++v) acc1[v] = accS[v];

    {
        const half_t* A1 = W1 + (size_t)(wm * 16 + l16) * 128 + quad * 8;
        #pragma unroll
        for (int k0 = 0; k0 < 128; k0 += 32) {
            h8_t ah, bh[3];
            ah = *(const h8_t*)(A1 + k0);
            int lc = (k0 >> 3) + quad;
            #pragma unroll
            for (int v = 0; v < 3; ++v)
                bh[v] = *(const h8_t*)(a1L + (v * 16 + l16) * 128 + ((lc ^ (l16 & 7)) * 8));
            #pragma unroll
            for (int v = 0; v < 3; ++v)
                acc1[v] = __builtin_amdgcn_mfma_f32_16x16x32_f16(ah, bh[v], acc1[v], 0, 0, 0);
        }
    }

    const size_t slot = (size_t)b * 64 + nt;
    {
        int o = wm * 16 + quad * 4;
        f4_t d[3];
        #pragma unroll
        for (int v = 0; v < 3; ++v) {
            d[v] = acc1[v];
            if (!FIRST) {
                #pragma unroll
                for (int e = 0; e < 4; ++e) d[v][e] += plWs[v * 128 + o + e];
            }
            if (WRITE_OUT)
                st4h(outH, (row0 + (size_t)v * N_) * 128 + o, d[v]);
        }
        #pragma unroll
        for (int v = 0; v < 3; ++v)
            #pragma unroll
            for (int e = 0; e < 4; ++e) {
                float s = d[v][e];
                s += __shfl_xor(s, 1);
                s += __shfl_xor(s, 2);
                s += __shfl_xor(s, 4);
                s += __shfl_xor(s, 8);
                d[v][e] = s;
            }
        if (l16 == 0) {
            #pragma unroll
            for (int v = 0; v < 3; ++v)
                #pragma unroll
                for (int e = 0; e < 4; ++e)
                    PpOut[slot * 384 + (size_t)(o + e) * 3 + v] = d[v][e];
        }
    }
}

// ---------------------------------------------------------------------------
// Final pool + final stage fused (fp32, exact; standalone, reads prev dispatch).
// ---------------------------------------------------------------------------
__global__ __launch_bounds__(128) void pool_final(const float* __restrict__ Pp,
                                                  const float* __restrict__ Wd,
                                                  const float* __restrict__ Wc,
                                                  float* __restrict__ out) {
    int b = blockIdx.x;
    int t = threadIdx.x;
    __shared__ float hid[H_][3];
    __shared__ float act[H_][3];
    {
        float s0 = 0.f, s1 = 0.f, s2 = 0.f;
        const float* p = Pp + (size_t)b * 64 * 384 + (size_t)t * 3;
        #pragma unroll 8
        for (int sl = 0; sl < 64; ++sl) {
            const float* q = p + (size_t)sl * 384;
            s0 += q[0]; s1 += q[1]; s2 += q[2];
        }
        const float inv = 1.0f / (float)N_;
        hid[t][0] = s0 * inv; hid[t][1] = s1 * inv; hid[t][2] = s2 * inv;
    }
    __syncthreads();

    float d0 = 0.f, d1 = 0.f, d2 = 0.f;
    const float* wd = Wd + (size_t)t * H_;
    for (int c = 0; c < H_; ++c) {
        float w = wd[c];
        d0 += w * hid[c][0]; d1 += w * hid[c][1]; d2 += w * hid[c][2];
    }
    float p0 = hid[t][0], p1 = hid[t][1], p2 = hid[t][2];
    float dot = p0 * d0 + p1 * d1 + p2 * d2;
    float dsq = d0 * d0 + d1 * d1 + d2 * d2 + EPS_;
    float cf = dot / dsq;
    float q0, q1, q2;
    if (dot >= 0.f) { q0 = p0; q1 = p1; q2 = p2; }
    else            { q0 = p0 - cf * d0; q1 = p1 - cf * d1; q2 = p2 - cf * d2; }
    act[t][0] = 0.2f * p0 + 0.8f * q0;
    act[t][1] = 0.2f * p1 + 0.8f * q1;
    act[t][2] = 0.2f * p2 + 0.8f * q2;
    __syncthreads();

    float o0 = 0.f, o1 = 0.f, o2 = 0.f;
    const float* wc = Wc + (size_t)t * H_;
    for (int c = 0; c < H_; ++c) {
        float w = wc[c];
        o0 += w * act[c][0]; o1 += w * act[c][1]; o2 += w * act[c][2];
    }
    size_t ob = ((size_t)b * H_ + t) * 3;
    out[ob + 0] = o0; out[ob + 1] = o1; out[ob + 2] = o2;
}

// ---------------------------------------------------------------------------
extern "C" void kernel_launch(void* const* d_in, const int* in_sizes, int n_in,
                              void* d_out, int out_size, void* d_ws, size_t ws_size,
                              hipStream_t stream) {
    const float* x   = (const float*)d_in[0];
    const float* Wf  = (const float*)d_in[1];
    const float* Wdp = (const float*)d_in[2];
    const float* Wfc = (const float*)d_in[3];
    const float* Wd0 = (const float*)d_in[4];
    const float* W0  = (const float*)d_in[5];
    const float* Wd1 = (const float*)d_in[6];
    const float* W1  = (const float*)d_in[7];
    const float* Wsc = (const float*)d_in[8];
    const float* Wda = (const float*)d_in[9];
    const float* Wc  = (const float*)d_in[10];
    float* out = (float*)d_out;
    (void)in_sizes; (void)n_in; (void)out_size; (void)ws_size;

    char* ws = (char*)d_ws;
    size_t off = 0;
    auto alloc = [&](size_t bytes) {
        void* p = ws + off;
        off = (off + bytes + 255) & ~(size_t)255;
        return p;
    };
    const size_t e128 = (size_t)R_ * 128;
    const size_t ppSl = (size_t)B_ * 64 * 384;
    half_t* wAll  = (half_t*)alloc((size_t)W_TOT * 2);
    half_t* h1F   = (half_t*)alloc(e128 * 2);
    half_t* hF[2] = { (half_t*)alloc(e128 * 2), (half_t*)alloc(e128 * 2) };
    float*  Pp    = (float*) alloc(4 * ppSl * 4);
    float*  WD0T  = (float*) alloc((size_t)TRD_TOT * 4);
    float*  WST   = (float*) alloc((size_t)TRS_TOT * 4);

    const half_t* whFc = wAll + OFF_FC;
    const half_t* whD0 = wAll + OFF_D0;
    const half_t* whW0 = wAll + OFF_W0;
    const half_t* whD1 = wAll + OFF_D1;
    const half_t* whW1 = wAll + OFF_W1;
    const half_t* whWs = wAll + OFF_WS;

    hipLaunchKernelGGL(prep, dim3(KNN_BLKS + CVT_BLKS + TR_BLKS), dim3(256), 0, stream,
                       x, Wf, Wdp, h1F, Wfc, Wd0, W0, Wd1, W1, Wsc, wAll, WD0T, WST);

    for (int i = 0; i < 4; ++i) {
        int cur = i & 1, prv = cur ^ 1;
        if (i == 0) {
            block_full<true, true><<<dim3(64, 1, 8), 512, 0, stream>>>(
                whFc, whD0, whW0, whD1, whWs, whW1,
                h1F, nullptr, nullptr, nullptr, hF[cur], Pp);
        } else if (i < 3) {
            block_full<false, true><<<dim3(64, 1, 8), 512, 0, stream>>>(
                whFc, whD0 + (size_t)i * 65536, whW0 + (size_t)i * 32768,
                whD1 + (size_t)i * 16384, whWs + (size_t)i * 32768,
                whW1 + (size_t)i * 16384,
                hF[prv], Pp + (size_t)(i - 1) * ppSl,
                WD0T + (size_t)(i - 1) * 32768, WST + (size_t)(i - 1) * 16384,
                hF[cur], Pp + (size_t)i * ppSl);
        } else {
            block_full<false, false><<<dim3(64, 1, 8), 512, 0, stream>>>(
                whFc, whD0 + (size_t)i * 65536, whW0 + (size_t)i * 32768,
                whD1 + (size_t)i * 16384, whWs + (size_t)i * 32768,
                whW1 + (size_t)i * 16384,
                hF[prv], Pp + (size_t)(i - 1) * ppSl,
                WD0T + (size_t)(i - 1) * 32768, WST + (size_t)(i - 1) * 16384,
                nullptr, Pp + (size_t)i * ppSl);
        }
    }
    hipLaunchKernelGGL(pool_final, dim3(B_), dim3(128), 0, stream,
                       Pp + (size_t)3 * ppSl, Wda, Wc, out);
}

// Round 13
// 209.954 us; speedup vs baseline: 1.0351x; 1.0047x over previous
//
#include <hip/hip_runtime.h>
#include <cfloat>
#include <cstdint>

#define B_   8
#define N_   1024
#define H_   128
#define K_   20
#define EPS_ 1e-6f
#define R_   (B_ * 3 * N_)

typedef _Float16 half_t;
typedef _Float16 h8_t __attribute__((ext_vector_type(8)));
typedef _Float16 h4_t __attribute__((ext_vector_type(4)));
typedef __attribute__((ext_vector_type(4))) float f4_t;

__device__ inline void st4h(half_t* __restrict__ p, size_t off, f4_t v) {
    h4_t o;
    o[0] = (half_t)v[0]; o[1] = (half_t)v[1]; o[2] = (half_t)v[2]; o[3] = (half_t)v[3];
    *(h4_t*)(p + off) = o;
}

#define OFF_FC 0
#define OFF_D0 32768
#define OFF_W0 294912
#define OFF_D1 425984
#define OFF_W1 491520
#define OFF_WS 557056
#define W_TOT  688128
#define KNN_BLKS (B_ * N_ / 4)
#define CVT_BLKS ((W_TOT + 255) / 256)
#define TRD_TOT  98304   /* 3 layers x 128 x 256 */
#define TRS_TOT  49152   /* 3 layers x 128 x 128 */
#define TR_BLKS  ((TRD_TOT + TRS_TOT) / 256)

// ---------------------------------------------------------------------------
// prep (R13): R12 + FULL unroll of the conv loop (K=20 compile-time) so all
// opw/ps LDS loads issue ahead and independent k-chains interleave. Order of
// accumulation preserved -> bit-identical.
// ---------------------------------------------------------------------------
__global__ __launch_bounds__(256) void prep(const float* __restrict__ x,
                                            const float* __restrict__ Wf,
                                            const float* __restrict__ Wd,
                                            half_t* __restrict__ h1,
                                            const float* __restrict__ Wfc,
                                            const float* __restrict__ Wd0,
                                            const float* __restrict__ W0,
                                            const float* __restrict__ Wd1,
                                            const float* __restrict__ W1,
                                            const float* __restrict__ Wsc,
                                            half_t* __restrict__ w,
                                            float* __restrict__ wd0t,
                                            float* __restrict__ wst) {
    __shared__ float ps[N_ * 3];
    __shared__ int opw[4][K_];
    int t = threadIdx.x;

    if (blockIdx.x >= KNN_BLKS + CVT_BLKS) {
        int j = (blockIdx.x - KNN_BLKS - CVT_BLKS) * 256 + t;
        if (j < TRD_TOT) {
            int L = j >> 15, rem = j & 32767;
            int c = rem >> 8, o = rem & 255;
            wd0t[j] = Wd0[(size_t)(L + 1) * 65536 + o * 256 + 128 + c];
        } else {
            int k = j - TRD_TOT;
            int L = k >> 14, rem = k & 16383;
            int c = rem >> 7, o = rem & 127;
            wst[k] = Wsc[(size_t)(L + 1) * 32768 + o * 256 + 128 + c];
        }
        return;
    }
    if (blockIdx.x >= KNN_BLKS) {
        int bid = blockIdx.x - KNN_BLKS;
        int i = bid * 256 + t;
        if (i < W_TOT) {
            const float* src; int off;
            if (i < OFF_W0)      { if (i < OFF_D0) { src = Wfc; off = OFF_FC; }
                                   else            { src = Wd0; off = OFF_D0; } }
            else if (i < OFF_W1) { if (i < OFF_D1) { src = W0;  off = OFF_W0; }
                                   else            { src = Wd1; off = OFF_D1; } }
            else                 { if (i < OFF_WS) { src = W1;  off = OFF_W1; }
                                   else            { src = Wsc; off = OFF_WS; } }
            w[i] = (half_t)src[i - off];
        }
        return;
    }

    int wv = t >> 6, lane = t & 63;
    int b = blockIdx.x >> 8;
    int n = (blockIdx.x & 255) * 4 + wv;

    const float4* xb4 = (const float4*)(x + (size_t)b * N_ * 3);
    float4* ps4 = (float4*)ps;
    #pragma unroll
    for (int i = 0; i < 3; ++i) ps4[t + i * 256] = xb4[t + i * 256];
    __syncthreads();

    const float cx = ps[3 * n + 0], cy = ps[3 * n + 1], cz = ps[3 * n + 2];
    uint ku[16];
    #pragma unroll
    for (int k = 0; k < 16; ++k) {
        int j = lane + (k << 6);
        const float* pj = ps + 3 * j;
        float dx = pj[0] - cx, dy = pj[1] - cy, dz = pj[2] - cz;
        float d = fmaf(dz, dz, fmaf(dy, dy, dx * dx));
        ku[k] = (__float_as_uint(d) & 0xFFFFFC00u) | (uint)j;
    }
    for (int s = 0; s < K_; ++s) {
        uint a0 = min(min(ku[0],  ku[1]),  ku[2]);
        uint a1 = min(min(ku[3],  ku[4]),  ku[5]);
        uint a2 = min(min(ku[6],  ku[7]),  ku[8]);
        uint a3 = min(min(ku[9],  ku[10]), ku[11]);
        uint a4 = min(min(ku[12], ku[13]), ku[14]);
        uint m  = min(min(min(a0, a1), min(a2, a3)), min(a4, ku[15]));
        // 16-lane row min via DPP row_ror (no DS latency)
        m = min(m, (uint)__builtin_amdgcn_update_dpp(0, (int)m, 0x121, 0xF, 0xF, true));
        m = min(m, (uint)__builtin_amdgcn_update_dpp(0, (int)m, 0x122, 0xF, 0xF, true));
        m = min(m, (uint)__builtin_amdgcn_update_dpp(0, (int)m, 0x124, 0xF, 0xF, true));
        m = min(m, (uint)__builtin_amdgcn_update_dpp(0, (int)m, 0x128, 0xF, 0xF, true));
        uint mm = min(min((uint)__builtin_amdgcn_readlane((int)m, 0),
                          (uint)__builtin_amdgcn_readlane((int)m, 16)),
                      min((uint)__builtin_amdgcn_readlane((int)m, 32),
                          (uint)__builtin_amdgcn_readlane((int)m, 48)));
        int j = (int)(mm & 1023u);
        if ((j & 63) == lane) {
            opw[wv][s] = j;
            ku[j >> 6] = 0xFFFFFFFFu;
        }
    }
    __syncthreads();

    float wf0[2], wf2[2], wd0c[2], wd2c[2];
    float bf[2][3], bg[2][3];
    #pragma unroll
    for (int c = 0; c < 2; ++c) {
        int ch = lane + c * 64;
        wf0[c]  = Wf[ch * 3 + 0];
        float wf1 = Wf[ch * 3 + 1];
        wf2[c]  = Wf[ch * 3 + 2];
        wd0c[c] = Wd[ch * 3 + 0];
        float wd1 = Wd[ch * 3 + 1];
        wd2c[c] = Wd[ch * 3 + 2];
        float df = wf1 - wf0[c], dg = wd1 - wd0c[c];
        bf[c][0] = df * cx; bf[c][1] = df * cy; bf[c][2] = df * cz;
        bg[c][0] = dg * cx; bg[c][1] = dg * cy; bg[c][2] = dg * cz;
    }
    float ax[2] = {0.f, 0.f}, ay[2] = {0.f, 0.f}, az[2] = {0.f, 0.f};
    #pragma unroll
    for (int k = 0; k < K_; ++k) {
        int j = opw[wv][k];
        const float* pj = ps + 3 * j;
        float nx = pj[0], ny = pj[1], nz = pj[2];
        float rx = fmaf(ny, cz, -(nz * cy));
        float ry = fmaf(nz, cx, -(nx * cz));
        float rz = fmaf(nx, cy, -(ny * cx));
        #pragma unroll
        for (int c = 0; c < 2; ++c) {
            float fx = fmaf(wf0[c], nx, fmaf(wf2[c], rx, bf[c][0]));
            float fy = fmaf(wf0[c], ny, fmaf(wf2[c], ry, bf[c][1]));
            float fz = fmaf(wf0[c], nz, fmaf(wf2[c], rz, bf[c][2]));
            float gx = fmaf(wd0c[c], nx, fmaf(wd2c[c], rx, bg[c][0]));
            float gy = fmaf(wd0c[c], ny, fmaf(wd2c[c], ry, bg[c][1]));
            float gz = fmaf(wd0c[c], nz, fmaf(wd2c[c], rz, bg[c][2]));
            float dot = fmaf(fz, gz, fmaf(fy, gy, fx * gx));
            float dsq = fmaf(gz, gz, fmaf(gy, gy, fmaf(gx, gx, EPS_)));
            float u = fminf(dot, 0.f) * __builtin_amdgcn_rcpf(dsq) * -0.8f;
            ax[c] = fmaf(u, gx, ax[c] + fx);
            ay[c] = fmaf(u, gy, ay[c] + fy);
            az[c] = fmaf(u, gz, az[c] + fz);
        }
    }
    const float inv = 1.0f / (float)K_;
    size_t r0 = ((size_t)b * 3) * N_ + n;
    #pragma unroll
    for (int c = 0; c < 2; ++c) {
        int ch = lane + c * 64;
        h1[(r0) * H_ + ch]          = (half_t)(ax[c] * inv);
        h1[(r0 + N_) * H_ + ch]     = (half_t)(ay[c] * inv);
        h1[(r0 + 2 * N_) * H_ + ch] = (half_t)(az[c] * inv);
    }
}

// ---------------------------------------------------------------------------
// Swizzled LDS helpers.
// ---------------------------------------------------------------------------
__device__ inline void stsw128(half_t* __restrict__ buf, int v, int n, int o, f4_t val) {
    int phys = (((o >> 3) ^ (n & 7)) * 8) + (o & 7);
    half_t* p = buf + (v * 16 + n) * 128 + phys;
    h4_t h;
    h[0] = (half_t)val[0]; h[1] = (half_t)val[1];
    h[2] = (half_t)val[2]; h[3] = (half_t)val[3];
    *(h4_t*)p = h;
}
__device__ inline f4_t ldsw128(const half_t* __restrict__ buf, int v, int n, int o) {
    int phys = (((o >> 3) ^ (n & 7)) * 8) + (o & 7);
    const half_t* p = buf + (v * 16 + n) * 128 + phys;
    h4_t x = *(const h4_t*)p;
    f4_t r;
    r[0] = (float)x[0]; r[1] = (float)x[1]; r[2] = (float)x[2]; r[3] = (float)x[3];
    return r;
}
__device__ inline void stsw256(half_t* __restrict__ buf, int v, int n, int o, f4_t val) {
    int phys = (((o >> 3) ^ (n & 7)) * 8) + (o & 7);
    half_t* p = buf + (v * 16 + n) * 256 + phys;
    h4_t h;
    h[0] = (half_t)val[0]; h[1] = (half_t)val[1];
    h[2] = (half_t)val[2]; h[3] = (half_t)val[3];
    *(h4_t*)p = h;
}
__device__ inline f4_t ldsw256(const half_t* __restrict__ buf, int v, int n, int o) {
    int phys = (((o >> 3) ^ (n & 7)) * 8) + (o & 7);
    const half_t* p = buf + (v * 16 + n) * 256 + phys;
    h4_t x = *(const h4_t*)p;
    f4_t r;
    r[0] = (float)x[0]; r[1] = (float)x[1]; r[2] = (float)x[2]; r[3] = (float)x[3];
    return r;
}

// ---------------------------------------------------------------------------
// block_full (R13): R12 + CONCURRENT prologue rowadd. plWs now runs on
// t in [256,384) (waves 4-5) instead of t<128 (serialized after plD0 on
// waves 0-1). Same per-output serial c-loop and expressions -> bit-identical;
// plD0 and plWs execute on disjoint waves concurrently.
// ---------------------------------------------------------------------------
template<bool FIRST, bool WRITE_OUT>
__global__ __launch_bounds__(512) void block_full(const half_t* __restrict__ Wfc,
                                                  const half_t* __restrict__ Wd0,
                                                  const half_t* __restrict__ W0,
                                                  const half_t* __restrict__ Wd1,
                                                  const half_t* __restrict__ Ws,
                                                  const half_t* __restrict__ W1,
                                                  const half_t* __restrict__ hprev,
                                                  const float* __restrict__ PpPrev,
                                                  const float* __restrict__ PW0,
                                                  const float* __restrict__ PW1,
                                                  half_t* __restrict__ outH,
                                                  float* __restrict__ PpOut) {
    __shared__ __align__(16) char smem[FIRST ? 49152 : 50688];
    half_t* hL   = (half_t*)(FIRST ? smem + 24576 : smem);
    half_t* HdL  = (half_t*)(smem);                               // FIRST only
    half_t* a0L  = (half_t*)(FIRST ? smem + 24576 : smem + 12288);
    half_t* netL = (half_t*)(FIRST ? smem : smem + 36864);
    half_t* a1L  = (half_t*)(FIRST ? smem + 12288 : smem + 24576);
    float* plP  = (float*)(smem + 12288);          // [3][128] (non-FIRST prologue)
    float* plD0 = (float*)(smem + 12288 + 1536);   // [3][256]
    float* plWs = (float*)(FIRST ? smem : smem + 49152); // unused for FIRST

    const int t = threadIdx.x;
    const int lane = t & 63, wm = t >> 6;            // wm in 0..7
    const int l16 = lane & 15, quad = lane >> 4;
    const int b  = blockIdx.z;
    const int nt = blockIdx.x;
    const int n0 = nt * 16;
    const size_t row0 = (size_t)(b * 3) * N_ + (n0 + l16);

    for (int c = t; c < 768; c += 512) {
        int v = c >> 8, rem = c & 255;
        int n = rem >> 4, ch = rem & 15;
        size_t g = (size_t)((b * 3 + v) * N_ + n0 + n) * 128 + ch * 8;
        *(uint4*)(hL + (v * 16 + n) * 128 + ((ch ^ (n & 7)) * 8)) =
            *(const uint4*)(hprev + g);
    }

    if (!FIRST) {
        // (a) pooled means: coalesced element-major read, identical slot order
        if (t < 384) {
            float sum = 0.f;
            const float* p = PpPrev + (size_t)b * 64 * 384 + t;
            #pragma unroll 32
            for (int sl = 0; sl < 64; ++sl) sum += p[(size_t)sl * 384];
            sum *= (1.0f / (float)N_);
            plP[(t % 3) * 128 + (t / 3)] = sum;
        }
        __syncthreads();   // hL staged + plP ready
        // (b) rowadd dots, transposed weights; plD0 (waves 0-3) and plWs
        // (waves 4-5) on disjoint waves, concurrent.
        if (t < 256) {
            float a0 = 0.f, a1 = 0.f, a2 = 0.f;
            #pragma unroll 16
            for (int c = 0; c < 128; ++c) {
                float w = PW0[(size_t)c * 256 + t];
                a0 += w * plP[c];
                a1 += w * plP[128 + c];
                a2 += w * plP[256 + c];
            }
            plD0[t] = a0; plD0[256 + t] = a1; plD0[512 + t] = a2;
        } else if (t < 384) {
            int t2 = t - 256;
            float a0 = 0.f, a1 = 0.f, a2 = 0.f;
            #pragma unroll 16
            for (int c = 0; c < 128; ++c) {
                float w = PW1[(size_t)c * 128 + t2];
                a0 += w * plP[c];
                a1 += w * plP[128 + c];
                a2 += w * plP[256 + c];
            }
            plWs[t2] = a0; plWs[128 + t2] = a1; plWs[256 + t2] = a2;
        }
    }
    __syncthreads();

    if (FIRST) {
        f4_t facc[3][2];
        #pragma unroll
        for (int v = 0; v < 3; ++v)
            #pragma unroll
            for (int i = 0; i < 2; ++i)
                #pragma unroll
                for (int e = 0; e < 4; ++e) facc[v][i][e] = 0.f;
        const half_t* Af = Wfc + (size_t)(wm * 32 + l16) * 128 + quad * 8;
        #pragma unroll
        for (int k0 = 0; k0 < 128; k0 += 32) {
            h8_t ah[2], bh[3];
            #pragma unroll
            for (int i = 0; i < 2; ++i)
                ah[i] = *(const h8_t*)(Af + (size_t)i * 2048 + k0);
            int lc = (k0 >> 3) + quad;
            #pragma unroll
            for (int v = 0; v < 3; ++v)
                bh[v] = *(const h8_t*)(hL + (v * 16 + l16) * 128 + ((lc ^ (l16 & 7)) * 8));
            #pragma unroll
            for (int v = 0; v < 3; ++v)
                #pragma unroll
                for (int i = 0; i < 2; ++i)
                    facc[v][i] = __builtin_amdgcn_mfma_f32_16x16x32_f16(
                        ah[i], bh[v], facc[v][i], 0, 0, 0);
        }
        __syncthreads();   // all hL reads done (hL dead hereafter; a0L overlays it)
        #pragma unroll
        for (int i = 0; i < 2; ++i) {
            int o = wm * 32 + i * 16 + quad * 4;
            #pragma unroll
            for (int v = 0; v < 3; ++v) stsw256(HdL, v, l16, o, facc[v][i]);
        }
        __syncthreads();
    }

    // accS: Ws*hidden accumulator (held to S3); same MFMA order as the old
    // standalone S3 Ws loop -> bit-identical.
    f4_t accS[3];
    #pragma unroll
    for (int v = 0; v < 3; ++v)
        #pragma unroll
        for (int e = 0; e < 4; ++e) accS[v][e] = 0.f;

    // S0 (+Ws fold): a0 = vnrelu(hidden, Wd0*hidden(+addD0)); accS += Ws*hidden
    {
        constexpr int C = FIRST ? 256 : 128;
        f4_t acc[3][2];
        #pragma unroll
        for (int v = 0; v < 3; ++v)
            #pragma unroll
            for (int i = 0; i < 2; ++i)
                #pragma unroll
                for (int e = 0; e < 4; ++e) acc[v][i][e] = 0.f;

        const half_t* Ad  = Wd0 + (size_t)(wm * 32 + l16) * 256 + quad * 8;
        const half_t* AsW = Ws  + (size_t)(wm * 16 + l16) * 256 + quad * 8;
        #pragma unroll
        for (int k0 = 0; k0 < C; k0 += 32) {
            h8_t ah[2], ahs, bh[3];
            #pragma unroll
            for (int i = 0; i < 2; ++i)
                ah[i] = *(const h8_t*)(Ad + (size_t)i * 4096 + k0);
            ahs = *(const h8_t*)(AsW + k0);
            int lc = (k0 >> 3) + quad;
            if (FIRST) {
                #pragma unroll
                for (int v = 0; v < 3; ++v)
                    bh[v] = *(const h8_t*)(HdL + (v * 16 + l16) * 256 + ((lc ^ (l16 & 7)) * 8));
            } else {
                #pragma unroll
                for (int v = 0; v < 3; ++v)
                    bh[v] = *(const h8_t*)(hL + (v * 16 + l16) * 128 + ((lc ^ (l16 & 7)) * 8));
            }
            #pragma unroll
            for (int v = 0; v < 3; ++v) {
                #pragma unroll
                for (int i = 0; i < 2; ++i)
                    acc[v][i] = __builtin_amdgcn_mfma_f32_16x16x32_f16(
                        ah[i], bh[v], acc[v][i], 0, 0, 0);
                accS[v] = __builtin_amdgcn_mfma_f32_16x16x32_f16(
                    ahs, bh[v], accS[v], 0, 0, 0);
            }
        }
        f4_t qs[2][3];
        #pragma unroll
        for (int i = 0; i < 2; ++i) {
            int o = wm * 32 + i * 16 + quad * 4;
            f4_t d[3], p[3];
            #pragma unroll
            for (int v = 0; v < 3; ++v) {
                d[v] = acc[v][i];
                if (!FIRST) {
                    #pragma unroll
                    for (int e = 0; e < 4; ++e) d[v][e] += plD0[v * 256 + o + e];
                }
            }
            if (FIRST) {
                #pragma unroll
                for (int v = 0; v < 3; ++v)
                    p[v] = ldsw256(HdL, v, l16, o);
            } else {
                if (o < 128) {
                    #pragma unroll
                    for (int v = 0; v < 3; ++v)
                        p[v] = ldsw128(hL, v, l16, o);
                } else {
                    #pragma unroll
                    for (int e = 0; e < 4; ++e) {
                        p[0][e] = plP[0 * 128 + o - 128 + e];
                        p[1][e] = plP[1 * 128 + o - 128 + e];
                        p[2][e] = plP[2 * 128 + o - 128 + e];
                    }
                }
            }
            #pragma unroll
            for (int e = 0; e < 4; ++e) {
                float dot = p[0][e] * d[0][e] + p[1][e] * d[1][e] + p[2][e] * d[2][e];
                float dsq = d[0][e] * d[0][e] + d[1][e] * d[1][e] + d[2][e] * d[2][e] + EPS_;
                float cf = dot / dsq;
                if (dot >= 0.f) {
                    qs[i][0][e] = p[0][e]; qs[i][1][e] = p[1][e]; qs[i][2][e] = p[2][e];
                } else {
                    qs[i][0][e] = p[0][e] - cf * d[0][e];
                    qs[i][1][e] = p[1][e] - cf * d[1][e];
                    qs[i][2][e] = p[2][e] - cf * d[2][e];
                }
            }
            if (FIRST) {   // a0L overlays dead hL only -> store directly
                #pragma unroll
                for (int v = 0; v < 3; ++v) stsw256(a0L, v, l16, o, qs[i][v]);
            }
        }
        if (!FIRST) {
            __syncthreads();   // all plP/plD0 reads done before a0L overwrite
            #pragma unroll
            for (int i = 0; i < 2; ++i) {
                int o = wm * 32 + i * 16 + quad * 4;
                #pragma unroll
                for (int v = 0; v < 3; ++v) stsw256(a0L, v, l16, o, qs[i][v]);
            }
        }
    }
    __syncthreads();

    // S1: net = W0 * a0
    f4_t acc1[3];
    #pragma unroll
    for (int v = 0; v < 3; ++v)
        #pragma unroll
        for (int e = 0; e < 4; ++e) acc1[v][e] = 0.f;

    {
        const half_t* Aw = W0 + (size_t)(wm * 16 + l16) * 256 + quad * 8;
        #pragma unroll
        for (int k0 = 0; k0 < 256; k0 += 32) {
            h8_t ah, bh[3];
            ah = *(const h8_t*)(Aw + k0);
            int lc = (k0 >> 3) + quad;
            #pragma unroll
            for (int v = 0; v < 3; ++v)
                bh[v] = *(const h8_t*)(a0L + (v * 16 + l16) * 256 + ((lc ^ (l16 & 7)) * 8));
            #pragma unroll
            for (int v = 0; v < 3; ++v)
                acc1[v] = __builtin_amdgcn_mfma_f32_16x16x32_f16(ah, bh[v], acc1[v], 0, 0, 0);
        }
    }
    __syncthreads();   // a0L reads done; (FIRST: netL overlays dead HdL)
    {
        int o = wm * 16 + quad * 4;
        #pragma unroll
        for (int v = 0; v < 3; ++v) stsw128(netL, v, l16, o, acc1[v]);
    }
    __syncthreads();

    // S2: a1 = vnrelu(net, Wd1*net)
    #pragma unroll
    for (int v = 0; v < 3; ++v)
        #pragma unroll
        for (int e = 0; e < 4; ++e) acc1[v][e] = 0.f;

    {
        const half_t* Ad1 = Wd1 + (size_t)(wm * 16 + l16) * 128 + quad * 8;
        #pragma unroll
        for (int k0 = 0; k0 < 128; k0 += 32) {
            h8_t ah, bh[3];
            ah = *(const h8_t*)(Ad1 + k0);
            int lc = (k0 >> 3) + quad;
            #pragma unroll
            for (int v = 0; v < 3; ++v)
                bh[v] = *(const h8_t*)(netL + (v * 16 + l16) * 128 + ((lc ^ (l16 & 7)) * 8));
            #pragma unroll
            for (int v = 0; v < 3; ++v)
                acc1[v] = __builtin_amdgcn_mfma_f32_16x16x32_f16(ah, bh[v], acc1[v], 0, 0, 0);
        }
    }
    {
        int o = wm * 16 + quad * 4;
        f4_t p[3], q[3];
        #pragma unroll
        for (int v = 0; v < 3; ++v) p[v] = ldsw128(netL, v, l16, o);
        #pragma unroll
        for (int e = 0; e < 4; ++e) {
            float dot = p[0][e] * acc1[0][e] + p[1][e] * acc1[1][e] + p[2][e] * acc1[2][e];
            float dsq = acc1[0][e] * acc1[0][e] + acc1[1][e] * acc1[1][e]
                      + acc1[2][e] * acc1[2][e] + EPS_;
            float cf = dot / dsq;
            if (dot >= 0.f) { q[0][e] = p[0][e]; q[1][e] = p[1][e]; q[2][e] = p[2][e]; }
            else {
                q[0][e] = p[0][e] - cf * acc1[0][e];
                q[1][e] = p[1][e] - cf * acc1[1][e];
                q[2][e] = p[2][e] - cf * acc1[2][e];
            }
        }
        #pragma unroll
        for (int v = 0; v < 3; ++v) stsw128(a1L, v, l16, o, q[v]);
    }
    __syncthreads();

    // S3: h = accS (Ws*hidden, already accumulated) + W1*a1 (+addWs)
    #pragma unroll
    for (int v = 0; v < 3; ++v) acc1[v] = accS[v];

    {
        const half_t* A1 = W1 + (size_t)(wm * 16 + l16) * 128 + quad * 8;
        #pragma unroll
        for (int k0 = 0; k0 < 128; k0 += 32) {
            h8_t ah, bh[3];
            ah = *(const h8_t*)(A1 + k0);
            int lc = (k0 >> 3) + quad;
            #pragma unroll
            for (int v = 0; v < 3; ++v)
                bh[v] = *(const h8_t*)(a1L + (v * 16 + l16) * 128 + ((lc ^ (l16 & 7)) * 8));
            #pragma unroll
            for (int v = 0; v < 3; ++v)
                acc1[v] = __builtin_amdgcn_mfma_f32_16x16x32_f16(ah, bh[v], acc1[v], 0, 0, 0);
        }
    }

    const size_t slot = (size_t)b * 64 + nt;
    {
        int o = wm * 16 + quad * 4;
        f4_t d[3];
        #pragma unroll
        for (int v = 0; v < 3; ++v) {
            d[v] = acc1[v];
            if (!FIRST) {
                #pragma unroll
                for (int e = 0; e < 4; ++e) d[v][e] += plWs[v * 128 + o + e];
            }
            if (WRITE_OUT)
                st4h(outH, (row0 + (size_t)v * N_) * 128 + o, d[v]);
        }
        #pragma unroll
        for (int v = 0; v < 3; ++v)
            #pragma unroll
            for (int e = 0; e < 4; ++e) {
                float s = d[v][e];
                s += __shfl_xor(s, 1);
                s += __shfl_xor(s, 2);
                s += __shfl_xor(s, 4);
                s += __shfl_xor(s, 8);
                d[v][e] = s;
            }
        if (l16 == 0) {
            #pragma unroll
            for (int v = 0; v < 3; ++v)
                #pragma unroll
                for (int e = 0; e < 4; ++e)
                    PpOut[slot * 384 + (size_t)(o + e) * 3 + v] = d[v][e];
        }
    }
}

// ---------------------------------------------------------------------------
// Final pool + final stage fused (fp32, exact; standalone, reads prev dispatch).
// ---------------------------------------------------------------------------
__global__ __launch_bounds__(128) void pool_final(const float* __restrict__ Pp,
                                                  const float* __restrict__ Wd,
                                                  const float* __restrict__ Wc,
                                                  float* __restrict__ out) {
    int b = blockIdx.x;
    int t = threadIdx.x;
    __shared__ float hid[H_][3];
    __shared__ float act[H_][3];
    {
        float s0 = 0.f, s1 = 0.f, s2 = 0.f;
        const float* p = Pp + (size_t)b * 64 * 384 + (size_t)t * 3;
        #pragma unroll 8
        for (int sl = 0; sl < 64; ++sl) {
            const float* q = p + (size_t)sl * 384;
            s0 += q[0]; s1 += q[1]; s2 += q[2];
        }
        const float inv = 1.0f / (float)N_;
        hid[t][0] = s0 * inv; hid[t][1] = s1 * inv; hid[t][2] = s2 * inv;
    }
    __syncthreads();

    float d0 = 0.f, d1 = 0.f, d2 = 0.f;
    const float* wd = Wd + (size_t)t * H_;
    for (int c = 0; c < H_; ++c) {
        float w = wd[c];
        d0 += w * hid[c][0]; d1 += w * hid[c][1]; d2 += w * hid[c][2];
    }
    float p0 = hid[t][0], p1 = hid[t][1], p2 = hid[t][2];
    float dot = p0 * d0 + p1 * d1 + p2 * d2;
    float dsq = d0 * d0 + d1 * d1 + d2 * d2 + EPS_;
    float cf = dot / dsq;
    float q0, q1, q2;
    if (dot >= 0.f) { q0 = p0; q1 = p1; q2 = p2; }
    else            { q0 = p0 - cf * d0; q1 = p1 - cf * d1; q2 = p2 - cf * d2; }
    act[t][0] = 0.2f * p0 + 0.8f * q0;
    act[t][1] = 0.2f * p1 + 0.8f * q1;
    act[t][2] = 0.2f * p2 + 0.8f * q2;
    __syncthreads();

    float o0 = 0.f, o1 = 0.f, o2 = 0.f;
    const float* wc = Wc + (size_t)t * H_;
    for (int c = 0; c < H_; ++c) {
        float w = wc[c];
        o0 += w * act[c][0]; o1 += w * act[c][1]; o2 += w * act[c][2];
    }
    size_t ob = ((size_t)b * H_ + t) * 3;
    out[ob + 0] = o0; out[ob + 1] = o1; out[ob + 2] = o2;
}

// ---------------------------------------------------------------------------
extern "C" void kernel_launch(void* const* d_in, const int* in_sizes, int n_in,
                              void* d_out, int out_size, void* d_ws, size_t ws_size,
                              hipStream_t stream) {
    const float* x   = (const float*)d_in[0];
    const float* Wf  = (const float*)d_in[1];
    const float* Wdp = (const float*)d_in[2];
    const float* Wfc = (const float*)d_in[3];
    const float* Wd0 = (const float*)d_in[4];
    const float* W0  = (const float*)d_in[5];
    const float* Wd1 = (const float*)d_in[6];
    const float* W1  = (const float*)d_in[7];
    const float* Wsc = (const float*)d_in[8];
    const float* Wda = (const float*)d_in[9];
    const float* Wc  = (const float*)d_in[10];
    float* out = (float*)d_out;
    (void)in_sizes; (void)n_in; (void)out_size; (void)ws_size;

    char* ws = (char*)d_ws;
    size_t off = 0;
    auto alloc = [&](size_t bytes) {
        void* p = ws + off;
        off = (off + bytes + 255) & ~(size_t)255;
        return p;
    };
    const size_t e128 = (size_t)R_ * 128;
    const size_t ppSl = (size_t)B_ * 64 * 384;
    half_t* wAll  = (half_t*)alloc((size_t)W_TOT * 2);
    half_t* h1F   = (half_t*)alloc(e128 * 2);
    half_t* hF[2] = { (half_t*)alloc(e128 * 2), (half_t*)alloc(e128 * 2) };
    float*  Pp    = (float*) alloc(4 * ppSl * 4);
    float*  WD0T  = (float*) alloc((size_t)TRD_TOT * 4);
    float*  WST   = (float*) alloc((size_t)TRS_TOT * 4);

    const half_t* whFc = wAll + OFF_FC;
    const half_t* whD0 = wAll + OFF_D0;
    const half_t* whW0 = wAll + OFF_W0;
    const half_t* whD1 = wAll + OFF_D1;
    const half_t* whW1 = wAll + OFF_W1;
    const half_t* whWs = wAll + OFF_WS;

    hipLaunchKernelGGL(prep, dim3(KNN_BLKS + CVT_BLKS + TR_BLKS), dim3(256), 0, stream,
                       x, Wf, Wdp, h1F, Wfc, Wd0, W0, Wd1, W1, Wsc, wAll, WD0T, WST);

    for (int i = 0; i < 4; ++i) {
        int cur = i & 1, prv = cur ^ 1;
        if (i == 0) {
            block_full<true, true><<<dim3(64, 1, 8), 512, 0, stream>>>(
                whFc, whD0, whW0, whD1, whWs, whW1,
                h1F, nullptr, nullptr, nullptr, hF[cur], Pp);
        } else if (i < 3) {
            block_full<false, true><<<dim3(64, 1, 8), 512, 0, stream>>>(
                whFc, whD0 + (size_t)i * 65536, whW0 + (size_t)i * 32768,
                whD1 + (size_t)i * 16384, whWs + (size_t)i * 32768,
                whW1 + (size_t)i * 16384,
                hF[prv], Pp + (size_t)(i - 1) * ppSl,
                WD0T + (size_t)(i - 1) * 32768, WST + (size_t)(i - 1) * 16384,
                hF[cur], Pp + (size_t)i * ppSl);
        } else {
            block_full<false, false><<<dim3(64, 1, 8), 512, 0, stream>>>(
                whFc, whD0 + (size_t)i * 65536, whW0 + (size_t)i * 32768,
                whD1 + (size_t)i * 16384, whWs + (size_t)i * 32768,
                whW1 + (size_t)i * 16384,
                hF[prv], Pp + (size_t)(i - 1) * ppSl,
                WD0T + (size_t)(i - 1) * 32768, WST + (size_t)(i - 1) * 16384,
                nullptr, Pp + (size_t)i * ppSl);
        }
    }
    hipLaunchKernelGGL(pool_final, dim3(B_), dim3(128), 0, stream,
                       Pp + (size_t)3 * ppSl, Wda, Wc, out);
}